// Round 12
// baseline (1567.306 us; speedup 1.0000x reference)
//
#include <hip/hip_runtime.h>
#include <math.h>

#define B_  64
#define T_  150
#define L_  256
#define H_  512
#define E_  512
#define V_  1000
#define G4_ 2048   // 4*H
#define DB_ 16     // producer blocks
#define HCB 32     // h-cols per producer block

typedef _Float16 f16;
typedef f16   f16x8 __attribute__((ext_vector_type(8)));
typedef f16   f16x4 __attribute__((ext_vector_type(4)));
typedef float f32x4 __attribute__((ext_vector_type(4)));
typedef unsigned long long ull;

__device__ __forceinline__ float sigmf(float x) { return 1.0f / (1.0f + expf(-x)); }

// =====================================================================
// Fused persistent kernel: 16 producer blocks (LSTM recurrence, R11
// structure) + 64 consumer blocks (per-b attention+output+logits+lsm).
// h history: xhist[t][b][128 ull] fp16, exchanged via relaxed AGENT
// atomics (coherence-point, no fences). tags[bb] = t+1 after step t.
// =====================================================================
__global__ __launch_bounds__(512) void fused_decoder(
    const int*   __restrict__ seq,      // [B][T]
    const float* __restrict__ G,        // [V][4H] pregate
    const float* __restrict__ Whh,      // [4H][H] fp32
    const float* __restrict__ cnn,      // [B][L][H] fp32
    const f16*   __restrict__ Vt16,     // [B][H][L] fp16 (cnn transposed)
    const f16*   __restrict__ Whm16,    // [512][512]
    const f16*   __restrict__ Wom16,    // [512][1024]
    const f16*   __restrict__ Wlogit16, // [1024][512] (rows>=1000 zero)
    const float* __restrict__ b_logit,  // [1000]
    ull*  __restrict__ xhist,           // [T+1][64][128] ull
    int*  __restrict__ tags,            // [16]
    float* __restrict__ out)            // [B][T][V]
{
    __shared__ __align__(16) char smem[140800];

    const int tid = threadIdx.x;
    const int bx  = blockIdx.x;
    const int ln  = tid & 63;
    const int wv  = tid >> 6;

    if (bx < DB_) {
        // ================= PRODUCER (R11 structure) =================
        f16   (*hlds)[520] = (f16(*)[520])smem;                 // 66,560
        float (*glds)[132] = (float(*)[132])(smem + 66560);     // 33,792
        float (*csh)[36]   = (float(*)[36])(smem + 100352);     //  9,216
        const int bb  = bx;
        const int mh  = wv >> 2;
        const int nt2 = wv & 3;

        // one-time: B fragments global -> registers
        f16x8 bfr[2][16];
        #pragma unroll
        for (int j = 0; j < 2; ++j) {
            const int n = 2 * nt2 + j;
            const int grow = (n >> 1) * H_ + bb * HCB + (n & 1) * 16 + (ln & 15);
            #pragma unroll
            for (int kt = 0; kt < 16; ++kt) {
                const int k0 = kt * 32 + (ln >> 4) * 8;
                float4 w0 = *(const float4*)(Whh + (size_t)grow * H_ + k0);
                float4 w1 = *(const float4*)(Whh + (size_t)grow * H_ + k0 + 4);
                bfr[j][kt] = (f16x8){(f16)w0.x, (f16)w0.y, (f16)w0.z, (f16)w0.w,
                                     (f16)w1.x, (f16)w1.y, (f16)w1.z, (f16)w1.w};
            }
        }
        for (int e = tid; e < 64 * 36; e += 512) ((float*)csh)[e] = 0.f;
        __syncthreads();

        const int cb = tid >> 3, cg = tid & 7;

        for (int t = 0; t < T_; ++t) {
            // G prefetch (independent of h; hides under poll)
            const int v = seq[cb * T_ + t];
            const float* gp = G + (size_t)v * G4_ + bb * HCB + cg * 4;
            float4 gq0 = *(const float4*)(gp);
            float4 gq1 = *(const float4*)(gp + H_);
            float4 gq2 = *(const float4*)(gp + 2 * H_);
            float4 gq3 = *(const float4*)(gp + 3 * H_);

            if (tid < DB_) {
                while (__hip_atomic_load(&tags[tid], __ATOMIC_RELAXED,
                                         __HIP_MEMORY_SCOPE_AGENT) < t) {}
            }
            __syncthreads();
            // bulk-load h^t (xhist[t]; t=0 slot pre-zeroed)
            const ull* src = xhist + (size_t)t * 8192;
            ull v0[8], v1[8];
            #pragma unroll
            for (int it = 0; it < 8; ++it) {
                const int e = tid + it * 512;
                const int b = e >> 6, s = e & 63;
                v0[it] = __hip_atomic_load(&src[b * 128 + 2 * s], __ATOMIC_RELAXED,
                                           __HIP_MEMORY_SCOPE_AGENT);
                v1[it] = __hip_atomic_load(&src[b * 128 + 2 * s + 1], __ATOMIC_RELAXED,
                                           __HIP_MEMORY_SCOPE_AGENT);
            }
            #pragma unroll
            for (int it = 0; it < 8; ++it) {
                const int e = tid + it * 512;
                const int b = e >> 6, s = e & 63;
                ull* dst = (ull*)&hlds[b][s * 8];
                dst[0] = v0[it]; dst[1] = v1[it];
            }
            __syncthreads();

            // gate GEMM: 2 M-tiles x 2 N-tiles per wave
            f32x4 acc00 = {0.f,0.f,0.f,0.f}, acc01 = {0.f,0.f,0.f,0.f};
            f32x4 acc10 = {0.f,0.f,0.f,0.f}, acc11 = {0.f,0.f,0.f,0.f};
            #pragma unroll
            for (int kt = 0; kt < 16; ++kt) {
                const int ko = kt * 32 + (ln >> 4) * 8;
                f16x8 a0 = *(const f16x8*)&hlds[(2 * mh)     * 16 + (ln & 15)][ko];
                f16x8 a1 = *(const f16x8*)&hlds[(2 * mh + 1) * 16 + (ln & 15)][ko];
                acc00 = __builtin_amdgcn_mfma_f32_16x16x32_f16(a0, bfr[0][kt], acc00, 0, 0, 0);
                acc01 = __builtin_amdgcn_mfma_f32_16x16x32_f16(a0, bfr[1][kt], acc01, 0, 0, 0);
                acc10 = __builtin_amdgcn_mfma_f32_16x16x32_f16(a1, bfr[0][kt], acc10, 0, 0, 0);
                acc11 = __builtin_amdgcn_mfma_f32_16x16x32_f16(a1, bfr[1][kt], acc11, 0, 0, 0);
            }
            {
                const int r0 = (2 * mh) * 16 + (ln >> 4) * 4;
                const int r1 = (2 * mh + 1) * 16 + (ln >> 4) * 4;
                const int c0 = (2 * nt2) * 16 + (ln & 15);
                const int c1 = (2 * nt2 + 1) * 16 + (ln & 15);
                #pragma unroll
                for (int i = 0; i < 4; ++i) {
                    glds[r0 + i][c0] = acc00[i];
                    glds[r0 + i][c1] = acc01[i];
                    glds[r1 + i][c0] = acc10[i];
                    glds[r1 + i][c1] = acc11[i];
                }
            }
            __syncthreads();

            // cell + direct publish into xhist[t+1]
            {
                float4 Gi = *(const float4*)&glds[cb][cg * 4];
                float4 Gf = *(const float4*)&glds[cb][32 + cg * 4];
                float4 Gg = *(const float4*)&glds[cb][64 + cg * 4];
                float4 Go = *(const float4*)&glds[cb][96 + cg * 4];
                float4 cold = *(const float4*)&csh[cb][cg * 4];
                float gi[4] = {Gi.x + gq0.x, Gi.y + gq0.y, Gi.z + gq0.z, Gi.w + gq0.w};
                float gf[4] = {Gf.x + gq1.x, Gf.y + gq1.y, Gf.z + gq1.z, Gf.w + gq1.w};
                float gg[4] = {Gg.x + gq2.x, Gg.y + gq2.y, Gg.z + gq2.z, Gg.w + gq2.w};
                float go[4] = {Go.x + gq3.x, Go.y + gq3.y, Go.z + gq3.z, Go.w + gq3.w};
                float cl[4] = {cold.x, cold.y, cold.z, cold.w};
                float4 cnew;
                f16x4 hp;
                #pragma unroll
                for (int i = 0; i < 4; ++i) {
                    float c2 = sigmf(gf[i]) * cl[i] + sigmf(gi[i]) * tanhf(gg[i]);
                    float h2 = sigmf(go[i]) * tanhf(c2);
                    ((float*)&cnew)[i] = c2;
                    hp[i] = (f16)h2;
                }
                *(float4*)&csh[cb][cg * 4] = cnew;
                __hip_atomic_store(
                    &xhist[(size_t)(t + 1) * 8192 + cb * 128 + bb * 8 + cg],
                    __builtin_bit_cast(ull, hp),
                    __ATOMIC_RELAXED, __HIP_MEMORY_SCOPE_AGENT);
            }
            __syncthreads();   // drains vmcnt before s_barrier
            if (tid == 0)
                __hip_atomic_store(&tags[bb], t + 1, __ATOMIC_RELAXED,
                                   __HIP_MEMORY_SCOPE_AGENT);
        }
    } else {
        // ================= CONSUMER (one per batch element) =========
        const int b = bx - DB_;
        f16   (*hl)[520]  = (f16(*)[520])smem;                  // 16,640
        f16   (*ml)[520]  = (f16(*)[520])(smem + 16640);        // 16,640
        float (*sl)[260]  = (float(*)[260])(smem + 33280);      // 16,640
        f16   (*pl)[264]  = (f16(*)[264])(smem + 49920);        //  8,448
        f16   (*ol)[520]  = (f16(*)[520])(smem + 58368);        // 16,640
        float (*ll)[1028] = (float(*)[1028])(smem + 75008);     // 65,792

        const float* cnnb = cnn + (size_t)b * L_ * H_;
        const f16*   vtb  = Vt16 + (size_t)b * H_ * L_;
        const int ln15 = ln & 15;
        const int ln4  = (ln >> 4) * 8;
        const int lr4  = (ln >> 4) * 4;

        for (int t0 = 0; t0 < T_; t0 += 16) {
            const int NB = (T_ - t0 < 16) ? (T_ - t0) : 16;
            if (tid < DB_) {
                while (__hip_atomic_load(&tags[tid], __ATOMIC_RELAXED,
                                         __HIP_MEMORY_SCOPE_AGENT) < t0 + NB)
                    __builtin_amdgcn_s_sleep(8);
            }
            __syncthreads();
            // load h rows for this batch: xhist[t0+1 .. t0+NB][b][*]
            for (int e = tid; e < NB * 128; e += 512) {
                int tt = e >> 7, s = e & 127;
                ull v = __hip_atomic_load(
                    &xhist[(size_t)(t0 + 1 + tt) * 8192 + b * 128 + s],
                    __ATOMIC_RELAXED, __HIP_MEMORY_SCOPE_AGENT);
                *(ull*)&hl[tt][s * 4] = v;
            }
            __syncthreads();

            // ---- mapped = h @ Whm16^T : 4 N-tiles/wave
            {
                f32x4 acc[4] = {};
                for (int kt = 0; kt < 16; ++kt) {
                    f16x8 a = *(const f16x8*)&hl[ln15][kt * 32 + ln4];
                    #pragma unroll
                    for (int j = 0; j < 4; ++j) {
                        int n = wv * 64 + j * 16 + ln15;
                        f16x8 bf = *(const f16x8*)(Whm16 + (size_t)n * 512 + kt * 32 + ln4);
                        acc[j] = __builtin_amdgcn_mfma_f32_16x16x32_f16(a, bf, acc[j], 0, 0, 0);
                    }
                }
                #pragma unroll
                for (int j = 0; j < 4; ++j)
                    #pragma unroll
                    for (int i = 0; i < 4; ++i)
                        ml[lr4 + i][wv * 64 + j * 16 + ln15] = (f16)acc[j][i];
            }
            __syncthreads();
            // ---- S = mapped @ cnn[b]^T : 2 N-tiles/wave (B cast inline)
            {
                f32x4 acc[2] = {};
                for (int kt = 0; kt < 16; ++kt) {
                    f16x8 a = *(const f16x8*)&ml[ln15][kt * 32 + ln4];
                    #pragma unroll
                    for (int j = 0; j < 2; ++j) {
                        int l = wv * 32 + j * 16 + ln15;
                        float4 w0 = *(const float4*)(cnnb + (size_t)l * H_ + kt * 32 + ln4);
                        float4 w1 = *(const float4*)(cnnb + (size_t)l * H_ + kt * 32 + ln4 + 4);
                        f16x8 bf = {(f16)w0.x, (f16)w0.y, (f16)w0.z, (f16)w0.w,
                                    (f16)w1.x, (f16)w1.y, (f16)w1.z, (f16)w1.w};
                        acc[j] = __builtin_amdgcn_mfma_f32_16x16x32_f16(a, bf, acc[j], 0, 0, 0);
                    }
                }
                #pragma unroll
                for (int j = 0; j < 2; ++j)
                    #pragma unroll
                    for (int i = 0; i < 4; ++i)
                        sl[lr4 + i][wv * 32 + j * 16 + ln15] = acc[j][i];
            }
            __syncthreads();
            // ---- softmax rows (2 per wave) -> P fp16
            #pragma unroll
            for (int rr = 0; rr < 2; ++rr) {
                int r = wv * 2 + rr;
                float4 v = *(const float4*)&sl[r][ln * 4];
                float mx = fmaxf(fmaxf(v.x, v.y), fmaxf(v.z, v.w));
                #pragma unroll
                for (int off = 32; off; off >>= 1) mx = fmaxf(mx, __shfl_xor(mx, off));
                float e0 = expf(v.x - mx), e1 = expf(v.y - mx);
                float e2 = expf(v.z - mx), e3 = expf(v.w - mx);
                float s = e0 + e1 + e2 + e3;
                #pragma unroll
                for (int off = 32; off; off >>= 1) s += __shfl_xor(s, off);
                float inv = 1.f / s;
                f16x4 p = {(f16)(e0 * inv), (f16)(e1 * inv), (f16)(e2 * inv), (f16)(e3 * inv)};
                *(f16x4*)&pl[r][ln * 4] = p;
            }
            __syncthreads();
            // ---- ctx = P @ V (Vt16) : 4 N-tiles/wave, K=256 -> reuse ml
            {
                f32x4 acc[4] = {};
                for (int kt = 0; kt < 8; ++kt) {
                    f16x8 a = *(const f16x8*)&pl[ln15][kt * 32 + ln4];
                    #pragma unroll
                    for (int j = 0; j < 4; ++j) {
                        int n = wv * 64 + j * 16 + ln15;
                        f16x8 bf = *(const f16x8*)(vtb + (size_t)n * L_ + kt * 32 + ln4);
                        acc[j] = __builtin_amdgcn_mfma_f32_16x16x32_f16(a, bf, acc[j], 0, 0, 0);
                    }
                }
                __syncthreads();
                #pragma unroll
                for (int j = 0; j < 4; ++j)
                    #pragma unroll
                    for (int i = 0; i < 4; ++i)
                        ml[lr4 + i][wv * 64 + j * 16 + ln15] = (f16)acc[j][i];
            }
            __syncthreads();
            // ---- out = [ctx | h] @ Wom16^T : 4 N-tiles/wave, K=1024
            {
                f32x4 acc[4] = {};
                for (int kt = 0; kt < 32; ++kt) {
                    f16x8 a = (kt < 16)
                        ? *(const f16x8*)&ml[ln15][kt * 32 + ln4]
                        : *(const f16x8*)&hl[ln15][(kt - 16) * 32 + ln4];
                    #pragma unroll
                    for (int j = 0; j < 4; ++j) {
                        int n = wv * 64 + j * 16 + ln15;
                        f16x8 bf = *(const f16x8*)(Wom16 + (size_t)n * 1024 + kt * 32 + ln4);
                        acc[j] = __builtin_amdgcn_mfma_f32_16x16x32_f16(a, bf, acc[j], 0, 0, 0);
                    }
                }
                #pragma unroll
                for (int j = 0; j < 4; ++j)
                    #pragma unroll
                    for (int i = 0; i < 4; ++i)
                        ol[lr4 + i][wv * 64 + j * 16 + ln15] = (f16)acc[j][i];
            }
            __syncthreads();
            // ---- logits = out @ Wlogit16^T + bias : 8 N-tiles/wave
            {
                f32x4 acc[8] = {};
                for (int kt = 0; kt < 16; ++kt) {
                    f16x8 a = *(const f16x8*)&ol[ln15][kt * 32 + ln4];
                    #pragma unroll
                    for (int j = 0; j < 8; ++j) {
                        int n = wv * 128 + j * 16 + ln15;
                        f16x8 bf = *(const f16x8*)(Wlogit16 + (size_t)n * 512 + kt * 32 + ln4);
                        acc[j] = __builtin_amdgcn_mfma_f32_16x16x32_f16(a, bf, acc[j], 0, 0, 0);
                    }
                }
                #pragma unroll
                for (int j = 0; j < 8; ++j) {
                    int n = wv * 128 + j * 16 + ln15;
                    float bias = (n < V_) ? b_logit[n] : 0.f;
                    #pragma unroll
                    for (int i = 0; i < 4; ++i)
                        ll[lr4 + i][n] = acc[j][i] + bias;
                }
            }
            __syncthreads();
            // ---- log_softmax + store (2 rows per wave)
            #pragma unroll
            for (int rr = 0; rr < 2; ++rr) {
                int r = wv * 2 + rr;
                if (r < NB) {
                    float mx = -INFINITY;
                    for (int i = ln; i < V_; i += 64) mx = fmaxf(mx, ll[r][i]);
                    #pragma unroll
                    for (int off = 32; off; off >>= 1) mx = fmaxf(mx, __shfl_xor(mx, off));
                    float s = 0.f;
                    for (int i = ln; i < V_; i += 64) s += expf(ll[r][i] - mx);
                    #pragma unroll
                    for (int off = 32; off; off >>= 1) s += __shfl_xor(s, off);
                    float lse = mx + logf(s);
                    float* dst = out + ((size_t)b * T_ + t0 + r) * V_;
                    for (int i = ln; i < V_; i += 64) dst[i] = ll[r][i] - lse;
                }
            }
            __syncthreads();
        }
    }
}

// ---------------- fp16-MFMA NT GEMM (pregate table)
template<bool RELU_A>
__global__ __launch_bounds__(256) void gemm16_nt(
    const float* __restrict__ A1, const float* __restrict__ Bm,
    const float* __restrict__ bias1, const float* __restrict__ bias2,
    float* __restrict__ C, int M, int N, int K)
{
    __shared__ f16 As[64][40];
    __shared__ f16 Bs[64][40];
    const int tid = threadIdx.x;
    const int m0 = blockIdx.x * 64, n0 = blockIdx.y * 64;
    const int ln = tid & 63, wv = tid >> 6;
    const int lr = tid >> 2, lc8 = (tid & 3) * 8;
    f32x4 acc[4] = {};

    for (int kb = 0; kb < K; kb += 32) {
        int gm = m0 + lr;
        float4 a0 = make_float4(0.f, 0.f, 0.f, 0.f), a1 = a0;
        if (gm < M) {
            a0 = *(const float4*)(A1 + (size_t)gm * K + kb + lc8);
            a1 = *(const float4*)(A1 + (size_t)gm * K + kb + lc8 + 4);
        }
        if (RELU_A) {
            a0.x = fmaxf(a0.x, 0.f); a0.y = fmaxf(a0.y, 0.f);
            a0.z = fmaxf(a0.z, 0.f); a0.w = fmaxf(a0.w, 0.f);
            a1.x = fmaxf(a1.x, 0.f); a1.y = fmaxf(a1.y, 0.f);
            a1.z = fmaxf(a1.z, 0.f); a1.w = fmaxf(a1.w, 0.f);
        }
        f16x8 av = {(f16)a0.x, (f16)a0.y, (f16)a0.z, (f16)a0.w,
                    (f16)a1.x, (f16)a1.y, (f16)a1.z, (f16)a1.w};
        *(f16x8*)&As[lr][lc8] = av;

        int gn = n0 + lr;
        float4 b0 = make_float4(0.f, 0.f, 0.f, 0.f), b1 = b0;
        if (gn < N) {
            b0 = *(const float4*)(Bm + (size_t)gn * K + kb + lc8);
            b1 = *(const float4*)(Bm + (size_t)gn * K + kb + lc8 + 4);
        }
        f16x8 bv = {(f16)b0.x, (f16)b0.y, (f16)b0.z, (f16)b0.w,
                    (f16)b1.x, (f16)b1.y, (f16)b1.z, (f16)b1.w};
        *(f16x8*)&Bs[lr][lc8] = bv;
        __syncthreads();

        f16x8 af = *(const f16x8*)&As[wv * 16 + (ln & 15)][(ln >> 4) * 8];
        #pragma unroll
        for (int ntt = 0; ntt < 4; ++ntt) {
            f16x8 bf = *(const f16x8*)&Bs[ntt * 16 + (ln & 15)][(ln >> 4) * 8];
            acc[ntt] = __builtin_amdgcn_mfma_f32_16x16x32_f16(af, bf, acc[ntt], 0, 0, 0);
        }
        __syncthreads();
    }

    #pragma unroll
    for (int ntt = 0; ntt < 4; ++ntt)
        #pragma unroll
        for (int i = 0; i < 4; ++i) {
            int gm = m0 + wv * 16 + (ln >> 4) * 4 + i;
            int gn = n0 + ntt * 16 + (ln & 15);
            if (gm < M && gn < N) {
                float v = acc[ntt][i];
                if (bias1) v += bias1[gn];
                if (bias2) v += bias2[gn];
                C[(size_t)gm * N + gn] = v;
            }
        }
}

// ---------------- weight casts fp32 -> fp16 (Wlogit padded to 1024 rows)
__global__ __launch_bounds__(256) void wcast(
    const float* __restrict__ whm, const float* __restrict__ wom,
    const float* __restrict__ wlg,
    f16* __restrict__ o_whm, f16* __restrict__ o_wom, f16* __restrict__ o_wlg)
{
    const int stride = gridDim.x * 256;
    for (int i = blockIdx.x * 256 + threadIdx.x; i < 262144; i += stride)
        o_whm[i] = (f16)whm[i];
    for (int i = blockIdx.x * 256 + threadIdx.x; i < 524288; i += stride)
        o_wom[i] = (f16)wom[i];
    for (int i = blockIdx.x * 256 + threadIdx.x; i < 524288; i += stride)
        o_wlg[i] = (i < 512000) ? (f16)wlg[i] : (f16)0.f;
}

// ---------------- Vt16[b][j][l] = (f16)cnn[b][l][j]
__global__ __launch_bounds__(256) void vtrans(
    const float* __restrict__ cnn, f16* __restrict__ Vt16)
{
    __shared__ f16 tile[32][34];
    const int j0 = blockIdx.x * 32, l0 = blockIdx.y * 32, b = blockIdx.z;
    const int x = threadIdx.x & 31, y = threadIdx.x >> 5;
    for (int i = y; i < 32; i += 8)
        tile[i][x] = (f16)cnn[((size_t)b * L_ + l0 + i) * H_ + j0 + x];
    __syncthreads();
    for (int i = y; i < 32; i += 8)
        Vt16[((size_t)b * H_ + j0 + i) * L_ + l0 + x] = tile[x][i];
}

extern "C" void kernel_launch(void* const* d_in, const int* in_sizes, int n_in,
                              void* d_out, int out_size, void* d_ws, size_t ws_size,
                              hipStream_t stream)
{
    const float* cnn     = (const float*)d_in[0];
    const int*   seq     = (const int*)d_in[1];
    const float* embed   = (const float*)d_in[2];
    const float* W_ih    = (const float*)d_in[3];
    const float* b_ih    = (const float*)d_in[4];
    const float* W_hh    = (const float*)d_in[5];
    const float* b_hh    = (const float*)d_in[6];
    const float* W_hm    = (const float*)d_in[7];
    const float* W_om    = (const float*)d_in[8];
    const float* W_logit = (const float*)d_in[9];
    const float* b_logit = (const float*)d_in[10];
    float* out = (float*)d_out;

    char* ws = (char*)d_ws;
    float* G        = (float*)ws;                        //  8,192,000 B
    ull*   xhist    = (ull*)(ws + 8192000);              //  9,904,128 B (151*8192*8)
    f16*   Vt16     = (f16*)(ws + 8192000 + 9904128);    // 16,777,216 B
    f16*   Whm16    = (f16*)(ws + 34873344);             //    524,288 B
    f16*   Wom16    = (f16*)(ws + 35397632);             //  1,048,576 B
    f16*   Wlogit16 = (f16*)(ws + 36446208);             //  1,048,576 B
    int*   tags     = (int*)(ws + 37494784);             //         64 B

    hipMemsetAsync(tags, 0, DB_ * sizeof(int), stream);
    hipMemsetAsync(xhist, 0, 8192 * sizeof(ull), stream);   // h^0 = 0

    // pregate table: G[v][:] = relu(embed[v]) @ W_ih^T + b_ih + b_hh
    gemm16_nt<true><<<dim3(16, 32), 256, 0, stream>>>(
        embed, W_ih, b_ih, b_hh, G, V_, G4_, E_);
    // weight casts + cnn transpose
    wcast<<<512, 256, 0, stream>>>(W_hm, W_om, W_logit, Whm16, Wom16, Wlogit16);
    vtrans<<<dim3(16, 8, 64), 256, 0, stream>>>(cnn, Vt16);

    // fused persistent: 16 producers + 64 consumers
    fused_decoder<<<DB_ + B_, 512, 0, stream>>>(
        seq, G, W_hh, cnn, Vt16, Whm16, Wom16, Wlogit16, b_logit,
        xhist, tags, out);
}

// Round 13
// 1079.840 us; speedup vs baseline: 1.4514x; 1.4514x over previous
//
#include <hip/hip_runtime.h>
#include <math.h>

#define B_  64
#define T_  150
#define L_  256
#define H_  512
#define E_  512
#define V_  1000
#define G4_ 2048   // 4*H
#define DB_ 16     // decoder blocks
#define HCB 32     // h-cols per decoder block (DB_*HCB == H_)

typedef _Float16 f16;
typedef f16   f16x8 __attribute__((ext_vector_type(8)));
typedef f16   f16x4 __attribute__((ext_vector_type(4)));
typedef float f32x4 __attribute__((ext_vector_type(4)));
typedef unsigned int u32x4 __attribute__((ext_vector_type(4)));
typedef unsigned long long ull;

__device__ __forceinline__ float sigmf(float x) { return 1.0f / (1.0f + expf(-x)); }

// 16B device-scope coherent load/store (same sc1 semantics the compiler emits
// for 8B agent-scope relaxed atomics, but dwordx4 width).
__device__ __forceinline__ u32x4 load16_sc1(const void* p)
{
    u32x4 r;
    asm volatile("global_load_dwordx4 %0, %1, off sc1"
                 : "=v"(r) : "v"(p) : "memory");
    return r;
}
__device__ __forceinline__ void store16_sc1(void* p, u32x4 v)
{
    asm volatile("global_store_dwordx4 %0, %1, off sc1"
                 :: "v"(p), "v"(v) : "memory");
}

// ---------------- fence-free persistent LSTM decoder (MFMA, 16 blocks) -----
// R11 structure; exchange widened to 16B sc1 ops. Block bb owns h-cols
// [bb*32, bb*32+32) -> 128 gate rows; B-fragments in registers (32 x f16x8).
// Per step: G-prefetch | poll 16 tags | bulk-load h (16B sc1, reg-staged) |
// MFMA | cell (8 cols/thread, one 16B publish) | syncthreads (vmcnt drain) | tag.
__global__ __launch_bounds__(512) void decoder_mfma(
    const int*   __restrict__ seq,    // [B][T]
    const float* __restrict__ G,      // [V][4H] pregate table
    const float* __restrict__ Whh,    // [4H][H] fp32
    f16*  __restrict__ xh,            // [2][64][512] fp16
    int*  __restrict__ tags,          // [16] monotone step tags
    float* __restrict__ hbuf)         // rows (t,b): [T*B][H]
{
    __shared__ __align__(16) f16   hlds[64][520];    // h fp16, 65 KB
    __shared__ __align__(16) float glds[64][132];    // gates fp32, 33.8 KB
    __shared__ __align__(16) float csh[64][36];      // c-state, 9.2 KB

    const int tid = threadIdx.x;
    const int bb  = blockIdx.x;
    const int ln  = tid & 63;
    const int wv  = tid >> 6;
    const int mh  = wv >> 2;           // 0..1 -> M-tiles {2mh, 2mh+1}
    const int nt2 = wv & 3;            // 0..3 -> N-tiles {2nt2, 2nt2+1}

    // ---- one-time: B fragments global -> registers (fp32 -> fp16)
    f16x8 bfr[2][16];
    #pragma unroll
    for (int j = 0; j < 2; ++j) {
        const int n = 2 * nt2 + j;
        const int grow = (n >> 1) * H_ + bb * HCB + (n & 1) * 16 + (ln & 15);
        #pragma unroll
        for (int kt = 0; kt < 16; ++kt) {
            const int k0 = kt * 32 + (ln >> 4) * 8;
            float4 w0 = *(const float4*)(Whh + (size_t)grow * H_ + k0);
            float4 w1 = *(const float4*)(Whh + (size_t)grow * H_ + k0 + 4);
            bfr[j][kt] = (f16x8){(f16)w0.x, (f16)w0.y, (f16)w0.z, (f16)w0.w,
                                 (f16)w1.x, (f16)w1.y, (f16)w1.z, (f16)w1.w};
        }
    }
    // zero hlds / csh (t=0 state)
    for (int e = tid; e < 64 * 520 / 4; e += 512) ((ull*)hlds)[e] = 0ull;
    for (int e = tid; e < 64 * 36; e += 512) ((float*)csh)[e] = 0.f;
    __syncthreads();

    const int cb = tid >> 2, cg = tid & 3;   // cell role (tid<256): b, 8-col group

    for (int t = 0; t < T_; ++t) {
        // ---- G prefetch for THIS step (independent of h; hides under poll)
        float4 ga[4][2];
        if (tid < 256) {
            const int v = seq[cb * T_ + t];
            const float* gp = G + (size_t)v * G4_ + bb * HCB + cg * 8;
            #pragma unroll
            for (int q = 0; q < 4; ++q) {
                ga[q][0] = *(const float4*)(gp + q * H_);
                ga[q][1] = *(const float4*)(gp + q * H_ + 4);
            }
        }

        if (t > 0) {
            if (tid < DB_) {
                while (__hip_atomic_load(&tags[tid], __ATOMIC_RELAXED,
                                         __HIP_MEMORY_SCOPE_AGENT) < t) {}
            }
            __syncthreads();
            // ---- bulk-load h^t: 8 x 16B sc1 loads per thread, reg-staged
            const f16* src = xh + (size_t)(t & 1) * 64 * 512;
            u32x4 vv[8];
            #pragma unroll
            for (int it = 0; it < 8; ++it) {
                const int e = tid + it * 512;
                const int b = e >> 6, s = e & 63;
                vv[it] = load16_sc1(src + b * 512 + s * 8);
            }
            asm volatile("s_waitcnt vmcnt(0)" ::: "memory");
            #pragma unroll
            for (int it = 0; it < 8; ++it) {
                const int e = tid + it * 512;
                const int b = e >> 6, s = e & 63;
                *(u32x4*)&hlds[b][s * 8] = vv[it];
            }
            __syncthreads();
        }

        // ---- gate GEMM: 2 M-tiles x 2 N-tiles per wave, K=512
        f32x4 acc00 = {0.f,0.f,0.f,0.f}, acc01 = {0.f,0.f,0.f,0.f};
        f32x4 acc10 = {0.f,0.f,0.f,0.f}, acc11 = {0.f,0.f,0.f,0.f};
        #pragma unroll
        for (int kt = 0; kt < 16; ++kt) {
            const int ko = kt * 32 + (ln >> 4) * 8;
            f16x8 a0 = *(const f16x8*)&hlds[(2 * mh)     * 16 + (ln & 15)][ko];
            f16x8 a1 = *(const f16x8*)&hlds[(2 * mh + 1) * 16 + (ln & 15)][ko];
            acc00 = __builtin_amdgcn_mfma_f32_16x16x32_f16(a0, bfr[0][kt], acc00, 0, 0, 0);
            acc01 = __builtin_amdgcn_mfma_f32_16x16x32_f16(a0, bfr[1][kt], acc01, 0, 0, 0);
            acc10 = __builtin_amdgcn_mfma_f32_16x16x32_f16(a1, bfr[0][kt], acc10, 0, 0, 0);
            acc11 = __builtin_amdgcn_mfma_f32_16x16x32_f16(a1, bfr[1][kt], acc11, 0, 0, 0);
        }
        // C/D layout: col = lane&15, row = (lane>>4)*4 + reg
        {
            const int r0 = (2 * mh) * 16 + (ln >> 4) * 4;
            const int r1 = (2 * mh + 1) * 16 + (ln >> 4) * 4;
            const int c0 = (2 * nt2) * 16 + (ln & 15);
            const int c1 = (2 * nt2 + 1) * 16 + (ln & 15);
            #pragma unroll
            for (int i = 0; i < 4; ++i) {
                glds[r0 + i][c0] = acc00[i];
                glds[r0 + i][c1] = acc01[i];
                glds[r1 + i][c0] = acc10[i];
                glds[r1 + i][c1] = acc11[i];
            }
        }
        __syncthreads();

        // ---- cell: thread (cb, cols cg*8..cg*8+7); one 16B publish
        if (tid < 256) {
            float gi[8], gf[8], gg[8], go[8], cl[8];
            #pragma unroll
            for (int hh = 0; hh < 2; ++hh) {
                float4 Gi = *(const float4*)&glds[cb][cg * 8 + hh * 4];
                float4 Gf = *(const float4*)&glds[cb][32 + cg * 8 + hh * 4];
                float4 Gg = *(const float4*)&glds[cb][64 + cg * 8 + hh * 4];
                float4 Go = *(const float4*)&glds[cb][96 + cg * 8 + hh * 4];
                float4 cc = *(const float4*)&csh[cb][cg * 8 + hh * 4];
                #pragma unroll
                for (int i = 0; i < 4; ++i) {
                    gi[hh * 4 + i] = ((const float*)&Gi)[i] + ((const float*)&ga[0][hh])[i];
                    gf[hh * 4 + i] = ((const float*)&Gf)[i] + ((const float*)&ga[1][hh])[i];
                    gg[hh * 4 + i] = ((const float*)&Gg)[i] + ((const float*)&ga[2][hh])[i];
                    go[hh * 4 + i] = ((const float*)&Go)[i] + ((const float*)&ga[3][hh])[i];
                    cl[hh * 4 + i] = ((const float*)&cc)[i];
                }
            }
            float hv[8], cv[8];
            f16x8 hp;
            #pragma unroll
            for (int i = 0; i < 8; ++i) {
                float c2 = sigmf(gf[i]) * cl[i] + sigmf(gi[i]) * tanhf(gg[i]);
                float h2 = sigmf(go[i]) * tanhf(c2);
                cv[i] = c2; hv[i] = h2; hp[i] = (f16)h2;
            }
            *(float4*)&csh[cb][cg * 8]     = make_float4(cv[0], cv[1], cv[2], cv[3]);
            *(float4*)&csh[cb][cg * 8 + 4] = make_float4(cv[4], cv[5], cv[6], cv[7]);
            float* hb = hbuf + ((size_t)t * 64 + cb) * H_ + bb * HCB + cg * 8;
            *(float4*)hb       = make_float4(hv[0], hv[1], hv[2], hv[3]);
            *(float4*)(hb + 4) = make_float4(hv[4], hv[5], hv[6], hv[7]);
            store16_sc1(xh + (size_t)((t + 1) & 1) * 64 * 512 + cb * 512 + bb * HCB + cg * 8,
                        __builtin_bit_cast(u32x4, hp));
        }
        __syncthreads();   // drains vmcnt before s_barrier -> publishes complete
        if (tid == 0)
            __hip_atomic_store(&tags[bb], t + 1, __ATOMIC_RELAXED,
                               __HIP_MEMORY_SCOPE_AGENT);
    }
}

// ---------------- fp16-MFMA NT GEMM: C[M][N] = op([A1|A2])[M][K] @ Bm[N][K]^T
template<bool RELU_A, bool REMAP>
__global__ __launch_bounds__(256) void gemm16_nt(
    const float* __restrict__ A1, const float* __restrict__ A2,
    const float* __restrict__ Bm,
    const float* __restrict__ bias1, const float* __restrict__ bias2,
    float* __restrict__ C, int M, int N, int KA)
{
    __shared__ f16 As[64][40];
    __shared__ f16 Bs[64][40];
    const int tid = threadIdx.x;
    const int m0 = blockIdx.x * 64, n0 = blockIdx.y * 64;
    const int ln = tid & 63, wv = tid >> 6;
    const int lr = tid >> 2, lc8 = (tid & 3) * 8;
    const int K = A2 ? 2 * KA : KA;
    f32x4 acc[4] = {};

    for (int kb = 0; kb < K; kb += 32) {
        const float* Ap; int kk;
        if (kb < KA) { Ap = A1; kk = kb; } else { Ap = A2; kk = kb - KA; }
        int gm = m0 + lr;
        float4 a0 = make_float4(0.f, 0.f, 0.f, 0.f), a1 = a0;
        if (gm < M) {
            a0 = *(const float4*)(Ap + (size_t)gm * KA + kk + lc8);
            a1 = *(const float4*)(Ap + (size_t)gm * KA + kk + lc8 + 4);
        }
        if (RELU_A) {
            a0.x = fmaxf(a0.x, 0.f); a0.y = fmaxf(a0.y, 0.f);
            a0.z = fmaxf(a0.z, 0.f); a0.w = fmaxf(a0.w, 0.f);
            a1.x = fmaxf(a1.x, 0.f); a1.y = fmaxf(a1.y, 0.f);
            a1.z = fmaxf(a1.z, 0.f); a1.w = fmaxf(a1.w, 0.f);
        }
        f16x8 av = {(f16)a0.x, (f16)a0.y, (f16)a0.z, (f16)a0.w,
                    (f16)a1.x, (f16)a1.y, (f16)a1.z, (f16)a1.w};
        *(f16x8*)&As[lr][lc8] = av;

        int gn = n0 + lr;
        float4 b0 = make_float4(0.f, 0.f, 0.f, 0.f), b1 = b0;
        if (gn < N) {
            b0 = *(const float4*)(Bm + (size_t)gn * K + kb + lc8);
            b1 = *(const float4*)(Bm + (size_t)gn * K + kb + lc8 + 4);
        }
        f16x8 bv = {(f16)b0.x, (f16)b0.y, (f16)b0.z, (f16)b0.w,
                    (f16)b1.x, (f16)b1.y, (f16)b1.z, (f16)b1.w};
        *(f16x8*)&Bs[lr][lc8] = bv;
        __syncthreads();

        f16x8 af = *(const f16x8*)&As[wv * 16 + (ln & 15)][(ln >> 4) * 8];
        #pragma unroll
        for (int ntt = 0; ntt < 4; ++ntt) {
            f16x8 bf = *(const f16x8*)&Bs[ntt * 16 + (ln & 15)][(ln >> 4) * 8];
            acc[ntt] = __builtin_amdgcn_mfma_f32_16x16x32_f16(af, bf, acc[ntt], 0, 0, 0);
        }
        __syncthreads();
    }

    #pragma unroll
    for (int ntt = 0; ntt < 4; ++ntt)
        #pragma unroll
        for (int i = 0; i < 4; ++i) {
            int gm = m0 + wv * 16 + (ln >> 4) * 4 + i;
            int gn = n0 + ntt * 16 + (ln & 15);
            if (gm < M && gn < N) {
                float v = acc[ntt][i];
                if (bias1) v += bias1[gn];
                if (bias2) v += bias2[gn];
                size_t row = REMAP ? ((size_t)(gm & 63) * T_ + (gm >> 6)) : (size_t)gm;
                C[row * (size_t)N + gn] = v;
            }
        }
}

// ---------------- batched fp16-MFMA NT GEMM (fp32 A and B, inline cast)
// C[z][M][N] = A[z][M][K] @ B[z][N][K]^T with arbitrary strides.
__global__ __launch_bounds__(256) void gemm16_bt(
    const float* __restrict__ A, size_t lda, size_t azs,
    const float* __restrict__ Bm, size_t ldb, size_t bzs,
    float* __restrict__ C, size_t ldc, size_t czs, int M, int N, int K)
{
    A  += blockIdx.z * azs;
    Bm += blockIdx.z * bzs;
    C  += blockIdx.z * czs;
    __shared__ f16 As[64][40];
    __shared__ f16 Bs[64][40];
    const int tid = threadIdx.x;
    const int m0 = blockIdx.x * 64, n0 = blockIdx.y * 64;
    const int ln = tid & 63, wv = tid >> 6;
    const int lr = tid >> 2, lc8 = (tid & 3) * 8;
    f32x4 acc[4] = {};

    for (int kb = 0; kb < K; kb += 32) {
        int gm = m0 + lr;
        float4 a0 = make_float4(0.f, 0.f, 0.f, 0.f), a1 = a0;
        if (gm < M) {
            a0 = *(const float4*)(A + (size_t)gm * lda + kb + lc8);
            a1 = *(const float4*)(A + (size_t)gm * lda + kb + lc8 + 4);
        }
        f16x8 av = {(f16)a0.x, (f16)a0.y, (f16)a0.z, (f16)a0.w,
                    (f16)a1.x, (f16)a1.y, (f16)a1.z, (f16)a1.w};
        *(f16x8*)&As[lr][lc8] = av;

        int gn = n0 + lr;
        float4 b0 = make_float4(0.f, 0.f, 0.f, 0.f), b1 = b0;
        if (gn < N) {
            b0 = *(const float4*)(Bm + (size_t)gn * ldb + kb + lc8);
            b1 = *(const float4*)(Bm + (size_t)gn * ldb + kb + lc8 + 4);
        }
        f16x8 bv = {(f16)b0.x, (f16)b0.y, (f16)b0.z, (f16)b0.w,
                    (f16)b1.x, (f16)b1.y, (f16)b1.z, (f16)b1.w};
        *(f16x8*)&Bs[lr][lc8] = bv;
        __syncthreads();

        f16x8 af = *(const f16x8*)&As[wv * 16 + (ln & 15)][(ln >> 4) * 8];
        #pragma unroll
        for (int ntt = 0; ntt < 4; ++ntt) {
            f16x8 bf = *(const f16x8*)&Bs[ntt * 16 + (ln & 15)][(ln >> 4) * 8];
            acc[ntt] = __builtin_amdgcn_mfma_f32_16x16x32_f16(af, bf, acc[ntt], 0, 0, 0);
        }
        __syncthreads();
    }

    #pragma unroll
    for (int ntt = 0; ntt < 4; ++ntt)
        #pragma unroll
        for (int i = 0; i < 4; ++i) {
            int gm = m0 + wv * 16 + (ln >> 4) * 4 + i;
            int gn = n0 + ntt * 16 + (ln & 15);
            if (gm < M && gn < N)
                C[(size_t)gm * ldc + gn] = acc[ntt][i];
        }
}

// ---------------- NN GEMM: C[M][N] = A[M][K] @ B[K][N]  (ctx = att @ cnn)
__global__ __launch_bounds__(256) void gemm_nn(
    const float* __restrict__ A, size_t lda, size_t azs,
    const float* __restrict__ Bm, size_t ldb, size_t bzs,
    float* __restrict__ C, size_t ldc, size_t czs, int M, int N, int K)
{
    A  += blockIdx.z * azs;
    Bm += blockIdx.z * bzs;
    C  += blockIdx.z * czs;
    __shared__ __align__(16) float As[16][68];
    __shared__ __align__(16) float Bs[16][68];
    const int tid = threadIdx.x;
    const int m0 = blockIdx.x * 64;
    const int n0 = blockIdx.y * 64;
    const int lr = tid >> 2;
    const int lc = (tid & 3) << 2;
    const int br = tid >> 4;
    const int bc = (tid & 15) << 2;
    const int tm = (tid & 15) << 2;
    const int tn = (tid >> 4) << 2;
    float acc[4][4] = {};

    for (int kb = 0; kb < K; kb += 16) {
        float4 a4 = make_float4(0.f, 0.f, 0.f, 0.f);
        int gm = m0 + lr;
        if (gm < M) a4 = *(const float4*)(A + (size_t)gm * lda + kb + lc);
        As[lc + 0][lr] = a4.x; As[lc + 1][lr] = a4.y;
        As[lc + 2][lr] = a4.z; As[lc + 3][lr] = a4.w;

        float4 b4 = make_float4(0.f, 0.f, 0.f, 0.f);
        if (n0 + bc < N) b4 = *(const float4*)(Bm + (size_t)(kb + br) * ldb + n0 + bc);
        Bs[br][bc + 0] = b4.x; Bs[br][bc + 1] = b4.y;
        Bs[br][bc + 2] = b4.z; Bs[br][bc + 3] = b4.w;
        __syncthreads();

        #pragma unroll
        for (int k = 0; k < 16; ++k) {
            float4 av = *(const float4*)&As[k][tm];
            float4 bv = *(const float4*)&Bs[k][tn];
            float af[4] = {av.x, av.y, av.z, av.w};
            float bf[4] = {bv.x, bv.y, bv.z, bv.w};
            #pragma unroll
            for (int i = 0; i < 4; ++i)
                #pragma unroll
                for (int j = 0; j < 4; ++j)
                    acc[i][j] += af[i] * bf[j];
        }
        __syncthreads();
    }

    #pragma unroll
    for (int i = 0; i < 4; ++i) {
        int gm = m0 + tm + i;
        if (gm >= M) continue;
        #pragma unroll
        for (int j = 0; j < 4; ++j) {
            int gn = n0 + tn + j;
            if (gn >= N) continue;
            C[(size_t)gm * ldc + gn] = acc[i][j];
        }
    }
}

// ---------------- softmax over rows of 256 (attention weights), 4 rows/block
__global__ __launch_bounds__(256) void att_softmax(float* __restrict__ att, int nrows)
{
    const int tid = threadIdx.x, lane = tid & 63, wave = tid >> 6;
    const int row = blockIdx.x * 4 + wave;
    if (row >= nrows) return;
    float4* p = (float4*)(att + (size_t)row * L_);
    float4 sc = p[lane];
    float mx = fmaxf(fmaxf(sc.x, sc.y), fmaxf(sc.z, sc.w));
    #pragma unroll
    for (int off = 32; off; off >>= 1) mx = fmaxf(mx, __shfl_xor(mx, off));
    float e0 = expf(sc.x - mx), e1 = expf(sc.y - mx);
    float e2 = expf(sc.z - mx), e3 = expf(sc.w - mx);
    float s = e0 + e1 + e2 + e3;
    #pragma unroll
    for (int off = 32; off; off >>= 1) s += __shfl_xor(s, off);
    float inv = 1.f / s;
    p[lane] = make_float4(e0 * inv, e1 * inv, e2 * inv, e3 * inv);
}

// ---------------- per-row log_softmax over V=1000, in place
__global__ __launch_bounds__(256) void logsoftmax_k(float* __restrict__ out)
{
    const int row = blockIdx.x;
    float* p = out + (size_t)row * V_;
    const int tid = threadIdx.x, lane = tid & 63, wave = tid >> 6;
    __shared__ float red[8];

    float vals[4];
    int n = 0;
    float mx = -INFINITY;
    for (int v = tid; v < V_; v += 256) { vals[n] = p[v]; mx = fmaxf(mx, vals[n]); ++n; }
    #pragma unroll
    for (int off = 32; off; off >>= 1) mx = fmaxf(mx, __shfl_xor(mx, off));
    if (lane == 0) red[wave] = mx;
    __syncthreads();
    mx = fmaxf(fmaxf(red[0], red[1]), fmaxf(red[2], red[3]));

    float s = 0.f;
    for (int i = 0; i < n; ++i) s += expf(vals[i] - mx);
    #pragma unroll
    for (int off = 32; off; off >>= 1) s += __shfl_xor(s, off);
    if (lane == 0) red[4 + wave] = s;
    __syncthreads();
    s = red[4] + red[5] + red[6] + red[7];

    const float lse = mx + logf(s);
    n = 0;
    for (int v = tid; v < V_; v += 256) { p[v] = vals[n] - lse; ++n; }
}

extern "C" void kernel_launch(void* const* d_in, const int* in_sizes, int n_in,
                              void* d_out, int out_size, void* d_ws, size_t ws_size,
                              hipStream_t stream)
{
    const float* cnn     = (const float*)d_in[0];
    const int*   seq     = (const int*)d_in[1];
    const float* embed   = (const float*)d_in[2];
    const float* W_ih    = (const float*)d_in[3];
    const float* b_ih    = (const float*)d_in[4];
    const float* W_hh    = (const float*)d_in[5];
    const float* b_hh    = (const float*)d_in[6];
    const float* W_hm    = (const float*)d_in[7];
    const float* W_om    = (const float*)d_in[8];
    const float* W_logit = (const float*)d_in[9];
    const float* b_logit = (const float*)d_in[10];
    float* out = (float*)d_out;

    float* ws = (float*)d_ws;
    float* G    = ws;                                  // 1000*2048 = 2,048,000
    float* hbuf = G + (size_t)V_ * G4_;                // 9600*512 (rows (t,b))
    float* outv = hbuf + (size_t)B_ * T_ * H_;         // 9600*512
    f16*   xh   = (f16*)(outv + (size_t)B_ * T_ * H_); // 2*64*512 f16 = 128 KB
    int*   tags = (int*)(xh + 2 * 64 * 512);           // 16 ints
    // scratch inside d_out (dead before the final logits write):
    float* mapped = out;                               // 9600*512; reused as ctx
    float* attb   = out + (size_t)B_ * T_ * H_;        // 9600*256

    hipMemsetAsync(tags, 0, DB_ * sizeof(int), stream);

    // pregate table: G[v][:] = relu(embed[v]) @ W_ih^T + b_ih + b_hh  (fp16 MFMA)
    gemm16_nt<true, false><<<dim3(16, 32), 256, 0, stream>>>(
        embed, nullptr, W_ih, b_ih, b_hh, G, V_, G4_, E_);

    // ---- Phase 1: fence-free MFMA persistent recurrence (16 blocks) ----
    decoder_mfma<<<DB_, 512, 0, stream>>>(seq, G, W_hh, xh, tags, hbuf);

    // ---- Phase 2: batched over all 9600 (t,b) rows ----
    // mapped = h @ W_hm^T   (fp16 MFMA)
    gemm16_nt<false, false><<<dim3(150, 8), 256, 0, stream>>>(
        hbuf, nullptr, W_hm, nullptr, nullptr, mapped, B_ * T_, H_, H_);
    // att[b][t][l] = mapped[(t,b)] . cnn[b][l]   (fp16 MFMA, batched)
    gemm16_bt<<<dim3(3, 4, 64), 256, 0, stream>>>(
        mapped, (size_t)B_ * H_, H_,
        cnn, H_, (size_t)L_ * H_,
        attb, L_, (size_t)T_ * L_, T_, L_, H_);
    att_softmax<<<(B_ * T_ + 3) / 4, 256, 0, stream>>>(attb, B_ * T_);
    // ctx = att @ cnn   (fp32, batched; overwrites mapped)
    gemm_nn<<<dim3(3, 8, 64), 256, 0, stream>>>(
        attb, L_, (size_t)T_ * L_,
        cnn, H_, (size_t)L_ * H_,
        mapped, (size_t)B_ * H_, H_, T_, H_, L_);
    // out = [ctx | h] @ W_om^T   (fp16 MFMA, fused K=1024)
    gemm16_nt<false, false><<<dim3(150, 8), 256, 0, stream>>>(
        mapped, hbuf, W_om, nullptr, nullptr, outv, B_ * T_, H_, H_);
    // logits (+bias), remap rows (t,b) -> (b,t)   (fp16 MFMA)
    gemm16_nt<false, true><<<dim3(150, 16), 256, 0, stream>>>(
        outv, nullptr, W_logit, b_logit, nullptr, out, B_ * T_, V_, H_);
    logsoftmax_k<<<B_ * T_, 256, 0, stream>>>(out);
}

// Round 14
// 1021.534 us; speedup vs baseline: 1.5343x; 1.0571x over previous
//
#include <hip/hip_runtime.h>
#include <math.h>

#define B_  64
#define T_  150
#define L_  256
#define H_  512
#define E_  512
#define V_  1000
#define G4_ 2048   // 4*H
#define DB_ 16     // decoder blocks
#define HCB 32     // h-cols per decoder block (DB_*HCB == H_)

typedef _Float16 f16;
typedef f16   f16x8 __attribute__((ext_vector_type(8)));
typedef f16   f16x4 __attribute__((ext_vector_type(4)));
typedef float f32x4 __attribute__((ext_vector_type(4)));
typedef unsigned long long ull;

__device__ __forceinline__ float sigmf(float x) { return 1.0f / (1.0f + expf(-x)); }

// ---------------- fence-free persistent LSTM decoder (R11, verified) -------
// Block bb owns h-cols [bb*32, bb*32+32) -> 128 gate rows. B-fragments loaded
// global->registers once (32 x f16x8). h exchange: 8B relaxed AGENT atomics
// (coherence-point, no fences). Per step: G-prefetch | poll 16 tags |
// bulk-load h (reg-staged) | MFMA | cell (4 cols/thread, direct publish) | tag.
__global__ __launch_bounds__(512) void decoder_mfma(
    const int*   __restrict__ seq,    // [B][T]
    const float* __restrict__ G,      // [V][4H] pregate table
    const float* __restrict__ Whh,    // [4H][H] fp32
    ull*  __restrict__ xh,            // [2][64][128] packed fp16 x4
    int*  __restrict__ tags,          // [16] monotone step tags
    float* __restrict__ hbuf)         // rows (t,b): [T*B][H]
{
    __shared__ f16   hlds[64][520];    // h fp16, 65 KB
    __shared__ float glds[64][132];    // gates fp32, 33.8 KB
    __shared__ float csh[64][36];      // c-state, 9.2 KB

    const int tid = threadIdx.x;
    const int bb  = blockIdx.x;
    const int ln  = tid & 63;
    const int wv  = tid >> 6;
    const int mh  = wv >> 2;           // 0..1 -> M-tiles {2mh, 2mh+1}
    const int nt2 = wv & 3;            // 0..3 -> N-tiles {2nt2, 2nt2+1}

    // ---- one-time: B fragments global -> registers (fp32 -> fp16)
    f16x8 bfr[2][16];
    #pragma unroll
    for (int j = 0; j < 2; ++j) {
        const int n = 2 * nt2 + j;
        const int grow = (n >> 1) * H_ + bb * HCB + (n & 1) * 16 + (ln & 15);
        #pragma unroll
        for (int kt = 0; kt < 16; ++kt) {
            const int k0 = kt * 32 + (ln >> 4) * 8;
            float4 w0 = *(const float4*)(Whh + (size_t)grow * H_ + k0);
            float4 w1 = *(const float4*)(Whh + (size_t)grow * H_ + k0 + 4);
            bfr[j][kt] = (f16x8){(f16)w0.x, (f16)w0.y, (f16)w0.z, (f16)w0.w,
                                 (f16)w1.x, (f16)w1.y, (f16)w1.z, (f16)w1.w};
        }
    }
    // zero hlds / csh
    for (int e = tid; e < 64 * 520 / 4; e += 512) ((ull*)hlds)[e] = 0ull;
    for (int e = tid; e < 64 * 36; e += 512) ((float*)csh)[e] = 0.f;
    __syncthreads();

    const int cb = tid >> 3, cg = tid & 7;   // cell role: b, col-quad (x8)

    for (int t = 0; t < T_; ++t) {
        // ---- G prefetch for THIS step (independent of h; hides under poll)
        const int v = seq[cb * T_ + t];
        const float* gp = G + (size_t)v * G4_ + bb * HCB + cg * 4;
        float4 gq0 = *(const float4*)(gp);
        float4 gq1 = *(const float4*)(gp + H_);
        float4 gq2 = *(const float4*)(gp + 2 * H_);
        float4 gq3 = *(const float4*)(gp + 3 * H_);

        if (t > 0) {
            if (tid < DB_) {
                while (__hip_atomic_load(&tags[tid], __ATOMIC_RELAXED,
                                         __HIP_MEMORY_SCOPE_AGENT) < t) {}
            }
            __syncthreads();
            // ---- bulk-load h^t: reg-stage 16 x 8B loads, then 8 x b128 writes
            const ull* src = xh + (size_t)(t & 1) * 64 * 128;
            ull v0[8], v1[8];
            #pragma unroll
            for (int it = 0; it < 8; ++it) {
                const int e = tid + it * 512;
                const int b = e >> 6, s = e & 63;
                v0[it] = __hip_atomic_load(&src[b * 128 + 2 * s], __ATOMIC_RELAXED,
                                           __HIP_MEMORY_SCOPE_AGENT);
                v1[it] = __hip_atomic_load(&src[b * 128 + 2 * s + 1], __ATOMIC_RELAXED,
                                           __HIP_MEMORY_SCOPE_AGENT);
            }
            #pragma unroll
            for (int it = 0; it < 8; ++it) {
                const int e = tid + it * 512;
                const int b = e >> 6, s = e & 63;
                ull* dst = (ull*)&hlds[b][s * 8];
                dst[0] = v0[it]; dst[1] = v1[it];
            }
            __syncthreads();
        }

        // ---- gate GEMM: 2 M-tiles x 2 N-tiles per wave, K=512
        f32x4 acc00 = {0.f,0.f,0.f,0.f}, acc01 = {0.f,0.f,0.f,0.f};
        f32x4 acc10 = {0.f,0.f,0.f,0.f}, acc11 = {0.f,0.f,0.f,0.f};
        #pragma unroll
        for (int kt = 0; kt < 16; ++kt) {
            const int ko = kt * 32 + (ln >> 4) * 8;
            f16x8 a0 = *(const f16x8*)&hlds[(2 * mh)     * 16 + (ln & 15)][ko];
            f16x8 a1 = *(const f16x8*)&hlds[(2 * mh + 1) * 16 + (ln & 15)][ko];
            acc00 = __builtin_amdgcn_mfma_f32_16x16x32_f16(a0, bfr[0][kt], acc00, 0, 0, 0);
            acc01 = __builtin_amdgcn_mfma_f32_16x16x32_f16(a0, bfr[1][kt], acc01, 0, 0, 0);
            acc10 = __builtin_amdgcn_mfma_f32_16x16x32_f16(a1, bfr[0][kt], acc10, 0, 0, 0);
            acc11 = __builtin_amdgcn_mfma_f32_16x16x32_f16(a1, bfr[1][kt], acc11, 0, 0, 0);
        }
        // C/D layout: col = lane&15, row = (lane>>4)*4 + reg
        {
            const int r0 = (2 * mh) * 16 + (ln >> 4) * 4;
            const int r1 = (2 * mh + 1) * 16 + (ln >> 4) * 4;
            const int c0 = (2 * nt2) * 16 + (ln & 15);
            const int c1 = (2 * nt2 + 1) * 16 + (ln & 15);
            #pragma unroll
            for (int i = 0; i < 4; ++i) {
                glds[r0 + i][c0] = acc00[i];
                glds[r0 + i][c1] = acc01[i];
                glds[r1 + i][c0] = acc10[i];
                glds[r1 + i][c1] = acc11[i];
            }
        }
        __syncthreads();

        // ---- cell: thread (cb, cols cg*4..cg*4+3); publish directly
        {
            float4 Gi = *(const float4*)&glds[cb][cg * 4];
            float4 Gf = *(const float4*)&glds[cb][32 + cg * 4];
            float4 Gg = *(const float4*)&glds[cb][64 + cg * 4];
            float4 Go = *(const float4*)&glds[cb][96 + cg * 4];
            float4 cold = *(const float4*)&csh[cb][cg * 4];
            float gi[4] = {Gi.x + gq0.x, Gi.y + gq0.y, Gi.z + gq0.z, Gi.w + gq0.w};
            float gf[4] = {Gf.x + gq1.x, Gf.y + gq1.y, Gf.z + gq1.z, Gf.w + gq1.w};
            float gg[4] = {Gg.x + gq2.x, Gg.y + gq2.y, Gg.z + gq2.z, Gg.w + gq2.w};
            float go[4] = {Go.x + gq3.x, Go.y + gq3.y, Go.z + gq3.z, Go.w + gq3.w};
            float cl[4] = {cold.x, cold.y, cold.z, cold.w};
            float4 cnew, hnew;
            f16x4 hp;
            #pragma unroll
            for (int i = 0; i < 4; ++i) {
                float c2 = sigmf(gf[i]) * cl[i] + sigmf(gi[i]) * tanhf(gg[i]);
                float h2 = sigmf(go[i]) * tanhf(c2);
                ((float*)&cnew)[i] = c2;
                ((float*)&hnew)[i] = h2;
                hp[i] = (f16)h2;
            }
            *(float4*)&csh[cb][cg * 4] = cnew;
            *(float4*)&hbuf[((size_t)t * 64 + cb) * H_ + bb * HCB + cg * 4] = hnew;
            __hip_atomic_store(
                &xh[(size_t)((t + 1) & 1) * 64 * 128 + cb * 128 + bb * 8 + cg],
                __builtin_bit_cast(ull, hp),
                __ATOMIC_RELAXED, __HIP_MEMORY_SCOPE_AGENT);
        }
        __syncthreads();   // compiler drains vmcnt before s_barrier
        if (tid == 0)
            __hip_atomic_store(&tags[bb], t + 1, __ATOMIC_RELAXED,
                               __HIP_MEMORY_SCOPE_AGENT);
    }
}

// ---------------- fp16-MFMA NT GEMM: C[M][N] = op([A1|A2])[M][K] @ Bm[N][K]^T
template<bool RELU_A, bool REMAP>
__global__ __launch_bounds__(256) void gemm16_nt(
    const float* __restrict__ A1, const float* __restrict__ A2,
    const float* __restrict__ Bm,
    const float* __restrict__ bias1, const float* __restrict__ bias2,
    float* __restrict__ C, int M, int N, int KA)
{
    __shared__ f16 As[64][40];
    __shared__ f16 Bs[64][40];
    const int tid = threadIdx.x;
    const int m0 = blockIdx.x * 64, n0 = blockIdx.y * 64;
    const int ln = tid & 63, wv = tid >> 6;
    const int lr = tid >> 2, lc8 = (tid & 3) * 8;
    const int K = A2 ? 2 * KA : KA;
    f32x4 acc[4] = {};

    for (int kb = 0; kb < K; kb += 32) {
        const float* Ap; int kk;
        if (kb < KA) { Ap = A1; kk = kb; } else { Ap = A2; kk = kb - KA; }
        int gm = m0 + lr;
        float4 a0 = make_float4(0.f, 0.f, 0.f, 0.f), a1 = a0;
        if (gm < M) {
            a0 = *(const float4*)(Ap + (size_t)gm * KA + kk + lc8);
            a1 = *(const float4*)(Ap + (size_t)gm * KA + kk + lc8 + 4);
        }
        if (RELU_A) {
            a0.x = fmaxf(a0.x, 0.f); a0.y = fmaxf(a0.y, 0.f);
            a0.z = fmaxf(a0.z, 0.f); a0.w = fmaxf(a0.w, 0.f);
            a1.x = fmaxf(a1.x, 0.f); a1.y = fmaxf(a1.y, 0.f);
            a1.z = fmaxf(a1.z, 0.f); a1.w = fmaxf(a1.w, 0.f);
        }
        f16x8 av = {(f16)a0.x, (f16)a0.y, (f16)a0.z, (f16)a0.w,
                    (f16)a1.x, (f16)a1.y, (f16)a1.z, (f16)a1.w};
        *(f16x8*)&As[lr][lc8] = av;

        int gn = n0 + lr;
        float4 b0 = make_float4(0.f, 0.f, 0.f, 0.f), b1 = b0;
        if (gn < N) {
            b0 = *(const float4*)(Bm + (size_t)gn * K + kb + lc8);
            b1 = *(const float4*)(Bm + (size_t)gn * K + kb + lc8 + 4);
        }
        f16x8 bv = {(f16)b0.x, (f16)b0.y, (f16)b0.z, (f16)b0.w,
                    (f16)b1.x, (f16)b1.y, (f16)b1.z, (f16)b1.w};
        *(f16x8*)&Bs[lr][lc8] = bv;
        __syncthreads();

        f16x8 af = *(const f16x8*)&As[wv * 16 + (ln & 15)][(ln >> 4) * 8];
        #pragma unroll
        for (int ntt = 0; ntt < 4; ++ntt) {
            f16x8 bf = *(const f16x8*)&Bs[ntt * 16 + (ln & 15)][(ln >> 4) * 8];
            acc[ntt] = __builtin_amdgcn_mfma_f32_16x16x32_f16(af, bf, acc[ntt], 0, 0, 0);
        }
        __syncthreads();
    }

    #pragma unroll
    for (int ntt = 0; ntt < 4; ++ntt)
        #pragma unroll
        for (int i = 0; i < 4; ++i) {
            int gm = m0 + wv * 16 + (ln >> 4) * 4 + i;
            int gn = n0 + ntt * 16 + (ln & 15);
            if (gm < M && gn < N) {
                float v = acc[ntt][i];
                if (bias1) v += bias1[gn];
                if (bias2) v += bias2[gn];
                size_t row = REMAP ? ((size_t)(gm & 63) * T_ + (gm >> 6)) : (size_t)gm;
                C[row * (size_t)N + gn] = v;
            }
        }
}

// ---------------- fused score GEMM + softmax: per (t-chunk, b)
// S[64][256] = mapped_rows @ cnn[b]^T (fp16 MFMA), row-softmax, write P fp16.
__global__ __launch_bounds__(512) void score_softmax(
    const float* __restrict__ mapped,  // rows (t,b), stride H
    const float* __restrict__ cnn,     // [B][L][H]
    f16* __restrict__ attP)            // [B][T][L] fp16 probabilities
{
    __shared__ f16   As[64][40];
    __shared__ f16   Bs[256][40];
    __shared__ float sl[64][260];

    const int tid = threadIdx.x;
    const int m0  = blockIdx.x * 64;
    const int b   = blockIdx.y;
    const int ln  = tid & 63, wv = tid >> 6;
    const int mh  = wv >> 2, nq = wv & 3;     // 2 M-tiles x 4 N-tiles per wave
    const int ln15 = ln & 15, ln4 = (ln >> 4) * 8;
    const float* cnnb = cnn + (size_t)b * L_ * H_;

    f32x4 acc[2][4] = {};

    for (int kb = 0; kb < H_; kb += 32) {
        // stage A: rows t = m0+lr (cast fp16)
        {
            int lr = tid >> 3, lc4 = (tid & 7) * 4;
            int t = m0 + lr;
            float4 a = make_float4(0.f, 0.f, 0.f, 0.f);
            if (t < T_) a = *(const float4*)(mapped + ((size_t)t * 64 + b) * H_ + kb + lc4);
            As[lr][lc4 + 0] = (f16)a.x; As[lr][lc4 + 1] = (f16)a.y;
            As[lr][lc4 + 2] = (f16)a.z; As[lr][lc4 + 3] = (f16)a.w;
        }
        // stage B: all 256 L-rows x 32 k
        {
            int br = tid >> 1, bc16 = (tid & 1) * 16;
            const float* src = cnnb + (size_t)br * H_ + kb + bc16;
            float4 w0 = *(const float4*)(src);
            float4 w1 = *(const float4*)(src + 4);
            float4 w2 = *(const float4*)(src + 8);
            float4 w3 = *(const float4*)(src + 12);
            f16x8 p0 = {(f16)w0.x, (f16)w0.y, (f16)w0.z, (f16)w0.w,
                        (f16)w1.x, (f16)w1.y, (f16)w1.z, (f16)w1.w};
            f16x8 p1 = {(f16)w2.x, (f16)w2.y, (f16)w2.z, (f16)w2.w,
                        (f16)w3.x, (f16)w3.y, (f16)w3.z, (f16)w3.w};
            *(f16x8*)&Bs[br][bc16]     = p0;
            *(f16x8*)&Bs[br][bc16 + 8] = p1;
        }
        __syncthreads();

        f16x8 a0 = *(const f16x8*)&As[(2 * mh)     * 16 + ln15][ln4];
        f16x8 a1 = *(const f16x8*)&As[(2 * mh + 1) * 16 + ln15][ln4];
        #pragma unroll
        for (int nj = 0; nj < 4; ++nj) {
            f16x8 bf = *(const f16x8*)&Bs[(nq * 4 + nj) * 16 + ln15][ln4];
            acc[0][nj] = __builtin_amdgcn_mfma_f32_16x16x32_f16(a0, bf, acc[0][nj], 0, 0, 0);
            acc[1][nj] = __builtin_amdgcn_mfma_f32_16x16x32_f16(a1, bf, acc[1][nj], 0, 0, 0);
        }
        __syncthreads();
    }

    // scatter S to sl
    #pragma unroll
    for (int mi = 0; mi < 2; ++mi)
        #pragma unroll
        for (int nj = 0; nj < 4; ++nj)
            #pragma unroll
            for (int i = 0; i < 4; ++i)
                sl[(2 * mh + mi) * 16 + (ln >> 4) * 4 + i][(nq * 4 + nj) * 16 + ln15]
                    = acc[mi][nj][i];
    __syncthreads();

    // softmax: 8 rows per wave
    #pragma unroll
    for (int rr = 0; rr < 8; ++rr) {
        int r = wv * 8 + rr;
        int t = m0 + r;
        if (t < T_) {
            float4 v = *(const float4*)&sl[r][ln * 4];
            float mx = fmaxf(fmaxf(v.x, v.y), fmaxf(v.z, v.w));
            #pragma unroll
            for (int off = 32; off; off >>= 1) mx = fmaxf(mx, __shfl_xor(mx, off));
            float e0 = expf(v.x - mx), e1 = expf(v.y - mx);
            float e2 = expf(v.z - mx), e3 = expf(v.w - mx);
            float s = e0 + e1 + e2 + e3;
            #pragma unroll
            for (int off = 32; off; off >>= 1) s += __shfl_xor(s, off);
            float inv = 1.f / s;
            f16x4 p = {(f16)(e0 * inv), (f16)(e1 * inv), (f16)(e2 * inv), (f16)(e3 * inv)};
            *(f16x4*)(attP + ((size_t)b * T_ + t) * L_ + ln * 4) = p;
        }
    }
}

// ---------------- ctx = P @ cnn[b] (NN, fp16 MFMA; B LDS-transposed tiles)
__global__ __launch_bounds__(256) void ctx16_nn(
    const f16* __restrict__ attP,   // [B][T][L]
    const float* __restrict__ cnn,  // [B][L][H]
    float* __restrict__ ctxout)     // rows (t,b): addr b*H + t*(B*H) + col
{
    __shared__ f16 As[64][40];
    __shared__ f16 Bs[64][40];
    const int tid = threadIdx.x;
    const int m0 = blockIdx.x * 64, n0 = blockIdx.y * 64;
    const int b  = blockIdx.z;
    const int ln = tid & 63, wv = tid >> 6;
    const int ln15 = ln & 15, ln4 = (ln >> 4) * 8;
    const float* cnnb = cnn + (size_t)b * L_ * H_;
    const f16*   pb   = attP + (size_t)b * T_ * L_;
    f32x4 acc[4] = {};

    for (int kb = 0; kb < L_; kb += 32) {
        // stage A: fp16 P rows t = m0+lr
        {
            int lr = tid >> 2, lc8 = (tid & 3) * 8;
            int t = m0 + lr;
            f16x8 av = {};
            if (t < T_) av = *(const f16x8*)(pb + (size_t)t * L_ + kb + lc8);
            *(f16x8*)&As[lr][lc8] = av;
        }
        // stage B transposed: Bs[n][k] = cnn[b][kb+k][n0+n]
        {
            int br = tid >> 3;              // k-row 0..31
            int nc = (tid & 7) * 8;         // n-group
            const float* src = cnnb + (size_t)(kb + br) * H_ + n0 + nc;
            float4 w0 = *(const float4*)(src);
            float4 w1 = *(const float4*)(src + 4);
            float wv8[8] = {w0.x, w0.y, w0.z, w0.w, w1.x, w1.y, w1.z, w1.w};
            #pragma unroll
            for (int j = 0; j < 8; ++j) Bs[nc + j][br] = (f16)wv8[j];
        }
        __syncthreads();

        f16x8 af = *(const f16x8*)&As[wv * 16 + ln15][ln4];
        #pragma unroll
        for (int ntt = 0; ntt < 4; ++ntt) {
            f16x8 bf = *(const f16x8*)&Bs[ntt * 16 + ln15][ln4];
            acc[ntt] = __builtin_amdgcn_mfma_f32_16x16x32_f16(af, bf, acc[ntt], 0, 0, 0);
        }
        __syncthreads();
    }

    #pragma unroll
    for (int ntt = 0; ntt < 4; ++ntt)
        #pragma unroll
        for (int i = 0; i < 4; ++i) {
            int t  = m0 + wv * 16 + (ln >> 4) * 4 + i;
            int gn = n0 + ntt * 16 + ln15;
            if (t < T_)
                ctxout[(size_t)b * H_ + (size_t)t * (B_ * H_) + gn] = acc[ntt][i];
        }
}

// ---------------- per-row log_softmax over V=1000, in place
__global__ __launch_bounds__(256) void logsoftmax_k(float* __restrict__ out)
{
    const int row = blockIdx.x;
    float* p = out + (size_t)row * V_;
    const int tid = threadIdx.x, lane = tid & 63, wave = tid >> 6;
    __shared__ float red[8];

    float vals[4];
    int n = 0;
    float mx = -INFINITY;
    for (int v = tid; v < V_; v += 256) { vals[n] = p[v]; mx = fmaxf(mx, vals[n]); ++n; }
    #pragma unroll
    for (int off = 32; off; off >>= 1) mx = fmaxf(mx, __shfl_xor(mx, off));
    if (lane == 0) red[wave] = mx;
    __syncthreads();
    mx = fmaxf(fmaxf(red[0], red[1]), fmaxf(red[2], red[3]));

    float s = 0.f;
    for (int i = 0; i < n; ++i) s += expf(vals[i] - mx);
    #pragma unroll
    for (int off = 32; off; off >>= 1) s += __shfl_xor(s, off);
    if (lane == 0) red[4 + wave] = s;
    __syncthreads();
    s = red[4] + red[5] + red[6] + red[7];

    const float lse = mx + logf(s);
    n = 0;
    for (int v = tid; v < V_; v += 256) { p[v] = vals[n] - lse; ++n; }
}

extern "C" void kernel_launch(void* const* d_in, const int* in_sizes, int n_in,
                              void* d_out, int out_size, void* d_ws, size_t ws_size,
                              hipStream_t stream)
{
    const float* cnn     = (const float*)d_in[0];
    const int*   seq     = (const int*)d_in[1];
    const float* embed   = (const float*)d_in[2];
    const float* W_ih    = (const float*)d_in[3];
    const float* b_ih    = (const float*)d_in[4];
    const float* W_hh    = (const float*)d_in[5];
    const float* b_hh    = (const float*)d_in[6];
    const float* W_hm    = (const float*)d_in[7];
    const float* W_om    = (const float*)d_in[8];
    const float* W_logit = (const float*)d_in[9];
    const float* b_logit = (const float*)d_in[10];
    float* out = (float*)d_out;

    float* ws = (float*)d_ws;
    float* G    = ws;                                  // 1000*2048 = 2,048,000
    float* hbuf = G + (size_t)V_ * G4_;                // 9600*512 (rows (t,b))
    float* outv = hbuf + (size_t)B_ * T_ * H_;         // 9600*512
    ull*   xh   = (ull*)(outv + (size_t)B_ * T_ * H_); // 2*64*128 ull
    int*   tags = (int*)(xh + 2 * 64 * 128);           // 16 ints
    // scratch inside d_out (dead before the final logits write):
    float* mapped = out;                               // 9600*512 fp32; reused as ctx
    f16*   attP   = (f16*)(out + (size_t)B_ * T_ * H_); // 9600*256 fp16

    hipMemsetAsync(tags, 0, DB_ * sizeof(int), stream);

    // pregate table: G[v][:] = relu(embed[v]) @ W_ih^T + b_ih + b_hh  (fp16 MFMA)
    gemm16_nt<true, false><<<dim3(16, 32), 256, 0, stream>>>(
        embed, nullptr, W_ih, b_ih, b_hh, G, V_, G4_, E_);

    // ---- Phase 1: fence-free MFMA persistent recurrence (16 blocks) ----
    decoder_mfma<<<DB_, 512, 0, stream>>>(seq, G, W_hh, xh, tags, hbuf);

    // ---- Phase 2: batched over all 9600 (t,b) rows ----
    // mapped = h @ W_hm^T   (fp16 MFMA)
    gemm16_nt<false, false><<<dim3(150, 8), 256, 0, stream>>>(
        hbuf, nullptr, W_hm, nullptr, nullptr, mapped, B_ * T_, H_, H_);
    // fused: S = mapped @ cnn[b]^T, softmax -> P fp16
    score_softmax<<<dim3(3, 64), 512, 0, stream>>>(mapped, cnn, attP);
    // ctx = P @ cnn[b]   (fp16 MFMA; overwrites mapped)
    ctx16_nn<<<dim3(3, 8, 64), 256, 0, stream>>>(attP, cnn, mapped);
    // out = [ctx | h] @ W_om^T   (fp16 MFMA, fused K=1024)
    gemm16_nt<false, false><<<dim3(150, 8), 256, 0, stream>>>(
        mapped, hbuf, W_om, nullptr, nullptr, outv, B_ * T_, H_, H_);
    // logits (+bias), remap rows (t,b) -> (b,t)   (fp16 MFMA)
    gemm16_nt<false, true><<<dim3(150, 16), 256, 0, stream>>>(
        outv, nullptr, W_logit, b_logit, nullptr, out, B_ * T_, V_, H_);
    logsoftmax_k<<<B_ * T_, 256, 0, stream>>>(out);
}